// Round 8
// baseline (16867.973 us; speedup 1.0000x reference)
//
#include <hip/hip_runtime.h>
#include <stdint.h>

typedef short short8 __attribute__((ext_vector_type(8)));
typedef float f32x4 __attribute__((ext_vector_type(4)));
typedef unsigned short u16;

#define MFMA16(a, b, c) __builtin_amdgcn_mfma_f32_16x16x32_bf16((a), (b), (c), 0, 0, 0)

#define T_LEN 512
#define BATCH 64
#define EMB_D 512
#define HID 1024
#define VOC 256
#define NWG 128
#define RNN_THREADS 512

// -------- workspace layout (bytes) --------
#define OFF_H0F   0u                         // float h0[2][64][1024]
#define OFF_H1F   524288u
#define OFF_H0B   1048576u                   // bf16 h0[2][64][1024]
#define OFF_H1B   1310720u
#define OFF_BAR   1572864u                   // barrier counter (in zeroed region)
#define ZERO_BYTES 1573120u
#define OFF_EMB   1573120u                   // bf16 emb_all[512][64][512]
#define OFF_WIH0  (OFF_EMB + 33554432u)
#define OFF_WHH0  (OFF_WIH0 + 3145728u)
#define OFF_WIH1  (OFF_WHH0 + 6291456u)
#define OFF_WHH1  (OFF_WIH1 + 6291456u)
#define OFF_WOUT  (OFF_WHH1 + 6291456u)
#define OFF_H1ALL (OFF_WOUT + 524288u)       // bf16 h1_all[512*64][1024]
#define WS_TOTAL  (OFF_H1ALL + 67108864u)

static __device__ __forceinline__ u16 f2b(float f) {
  uint32_t u = __float_as_uint(f);
  u += 0x7FFFu + ((u >> 16) & 1u);   // round-to-nearest-even
  return (u16)(u >> 16);
}
static __device__ __forceinline__ float sigm(float x) { return 1.0f / (1.0f + __expf(-x)); }

// -------- f32 -> bf16 convert --------
__global__ void cvt_kernel(const float* __restrict__ src, u16* __restrict__ dst, int n) {
  int i = ((int)blockIdx.x * 256 + (int)threadIdx.x) * 4;
  if (i + 4 <= n) {
    const float4 v = *(const float4*)(src + i);
    ushort4 o;
    o.x = f2b(v.x); o.y = f2b(v.y); o.z = f2b(v.z); o.w = f2b(v.w);
    *(ushort4*)(dst + i) = o;
  }
}

// -------- embedding gather --------
__global__ void emb_kernel(const int* __restrict__ x, const float* __restrict__ embed,
                           u16* __restrict__ emb_all) {
  const int r = (int)blockIdx.x * 4 + ((int)threadIdx.x >> 6);
  const int c = ((int)threadIdx.x & 63) * 8;
  const int t = r >> 6, b = r & 63;
  const int xi = x[b * T_LEN + t];
  const float* s = embed + (size_t)xi * EMB_D + c;
  const float4 v0 = *(const float4*)s;
  const float4 v1 = *(const float4*)(s + 4);
  ushort4 lo, hi;
  lo.x = f2b(v0.x); lo.y = f2b(v0.y); lo.z = f2b(v0.z); lo.w = f2b(v0.w);
  hi.x = f2b(v1.x); hi.y = f2b(v1.y); hi.z = f2b(v1.z); hi.w = f2b(v1.w);
  u16* d = emb_all + (size_t)r * EMB_D + c;
  *(ushort4*)d = lo;
  *(ushort4*)(d + 4) = hi;
}

// -------- persistent RNN: superstep s = layer0(t=s) || layer1(t=s-1) --------
// 128 WGs (1/CU guaranteed co-resident). Wave roles as R7 (validated):
// waves 0-3 = input-matrix K-slices, waves 4-7 = hidden-matrix K-slices.
// NEW vs R7: weights preloaded to VGPRs once (constant across 512 steps);
// outer time loop in-kernel with the R1-validated device-scope atomic barrier.
__global__ __launch_bounds__(RNN_THREADS, 2) void rnn_persist_kernel(
    const u16* __restrict__ emb_all,
    const u16* __restrict__ A0i_r, const u16* __restrict__ A0i_z, const u16* __restrict__ A0i_n,
    const u16* __restrict__ A0h_r, const u16* __restrict__ A0h_z, const u16* __restrict__ A0h_n,
    const u16* __restrict__ A1i_r, const u16* __restrict__ A1i_z, const u16* __restrict__ A1i_n,
    const u16* __restrict__ A1h_r, const u16* __restrict__ A1h_z, const u16* __restrict__ A1h_n,
    const float* __restrict__ bih0, const float* __restrict__ bhh0,
    const float* __restrict__ bih1, const float* __restrict__ bhh1,
    float* __restrict__ h0f, float* __restrict__ h1f,
    u16* __restrict__ h0b, u16* __restrict__ h1b,
    u16* __restrict__ h1all, unsigned* __restrict__ bar)
{
  __shared__ __align__(16) float lds[16384];  // [zone4][group4][bt4][lane64][reg4]
  const int tid = (int)threadIdx.x;
  const int wv = tid >> 6;
  const int lane = tid & 63;
  const int lrow = lane & 15;
  const int lk8 = (lane >> 4) << 3;
  const int layer = (int)(blockIdx.x >> 6);
  const int ubase = ((int)blockIdx.x & 63) << 4;
  const bool iwave = (wv < 4);
  const bool l0i = (layer == 0) && iwave;

  // ---- role-uniform A config (R7 structure: per-gate base pointers) ----
  const u16 *Ar, *Az, *An;
  int ldb, k0;
  if (layer == 0) {
    if (iwave) { Ar = A0i_r; Az = A0i_z; An = A0i_n; ldb = EMB_D; k0 = wv * 128; }
    else       { Ar = A0h_r; Az = A0h_z; An = A0h_n; ldb = HID;   k0 = (wv - 4) * 256; }
  } else {
    if (iwave) { Ar = A1i_r; Az = A1i_z; An = A1i_n; ldb = HID;   k0 = wv * 256; }
    else       { Ar = A1h_r; Az = A1h_z; An = A1h_n; ldb = HID;   k0 = (wv - 4) * 256; }
  }
  const size_t arow = (size_t)(ubase + lrow) * ldb;

  // ---- preload A fragments to registers (constant across time) ----
  short8 aR[8], aZ[8], aN[8];
  if (l0i) {
#pragma unroll
    for (int ks = 0; ks < 4; ++ks) {
      const int kk = k0 + ks * 32 + lk8;
      aR[ks] = *(const short8*)(Ar + arow + kk);
      aZ[ks] = *(const short8*)(Az + arow + kk);
      aN[ks] = *(const short8*)(An + arow + kk);
    }
  } else {
#pragma unroll
    for (int ks = 0; ks < 8; ++ks) {
      const int kk = k0 + ks * 32 + lk8;
      aR[ks] = *(const short8*)(Ar + arow + kk);
      aZ[ks] = *(const short8*)(Az + arow + kk);
      aN[ks] = *(const short8*)(An + arow + kk);
    }
  }

  // ---- preload epilogue bias combos (constant across time) ----
  const float* bi = layer ? bih1 : bih0;
  const float* bh = layer ? bhh1 : bhh0;
  float bR[2], bZ[2], bNi[2], bNh[2];
#pragma unroll
  for (int pp = 0; pp < 2; ++pp) {
    const int ug = ubase + ((tid + pp * RNN_THREADS) >> 6);
    bR[pp]  = bi[ug] + bh[ug];
    bZ[pp]  = bi[HID + ug] + bh[HID + ug];
    bNi[pp] = bi[2 * HID + ug];
    bNh[pp] = bh[2 * HID + ug];
  }
  float* hf = layer ? h1f : h0f;
  u16* hb = layer ? h1b : h0b;

  for (int s = 0; s <= T_LEN; ++s) {
    const bool active = (layer == 0) ? (s < T_LEN) : (s >= 1);
    if (active) {
      const int rdA = ((s + 1) & 1) * (BATCH * HID);  // h0(s-1) slot
      const u16* Bp;
      if (layer == 0) Bp = iwave ? (emb_all + (size_t)s * (BATCH * EMB_D)) : (h0b + rdA);
      else            Bp = iwave ? (h0b + rdA) : (h1b + (s & 1) * (BATCH * HID));

      f32x4 acc0[4], acc1[4], accn[4];
#pragma unroll
      for (int bt = 0; bt < 4; ++bt) {
        acc0[bt] = (f32x4){0.f, 0.f, 0.f, 0.f};
        acc1[bt] = (f32x4){0.f, 0.f, 0.f, 0.f};
        accn[bt] = (f32x4){0.f, 0.f, 0.f, 0.f};
      }
      if (l0i) {
#pragma unroll
        for (int ks = 0; ks < 4; ++ks) {
          const int kk = k0 + ks * 32 + lk8;
#pragma unroll
          for (int bt = 0; bt < 4; ++bt) {
            const short8 bf = *(const short8*)(Bp + (size_t)(bt * 16 + lrow) * EMB_D + kk);
            acc0[bt] = MFMA16(aR[ks], bf, acc0[bt]);
            acc1[bt] = MFMA16(aZ[ks], bf, acc1[bt]);
            accn[bt] = MFMA16(aN[ks], bf, accn[bt]);
          }
        }
      } else {
#pragma unroll
        for (int ks = 0; ks < 8; ++ks) {
          const int kk = k0 + ks * 32 + lk8;
#pragma unroll
          for (int bt = 0; bt < 4; ++bt) {
            const short8 bf = *(const short8*)(Bp + (size_t)(bt * 16 + lrow) * HID + kk);
            acc0[bt] = MFMA16(aR[ks], bf, acc0[bt]);
            acc1[bt] = MFMA16(aZ[ks], bf, acc1[bt]);
            accn[bt] = MFMA16(aN[ks], bf, accn[bt]);
          }
        }
      }
      // reduction round 1 (R7-validated): i-waves write zones, n -> group 2
      const f32x4 z4 = {0.f, 0.f, 0.f, 0.f};
      if (iwave) {
#pragma unroll
        for (int bt = 0; bt < 4; ++bt) {
          *(f32x4*)&lds[(((wv * 4 + 0) * 4 + bt) * 64 + lane) * 4] = acc0[bt];
          *(f32x4*)&lds[(((wv * 4 + 1) * 4 + bt) * 64 + lane) * 4] = acc1[bt];
          *(f32x4*)&lds[(((wv * 4 + 2) * 4 + bt) * 64 + lane) * 4] = accn[bt];
          *(f32x4*)&lds[(((wv * 4 + 3) * 4 + bt) * 64 + lane) * 4] = z4;
        }
      }
      __syncthreads();
      // reduction round 2: h-waves add, n -> group 3
      if (!iwave) {
        const int z = wv - 4;
#pragma unroll
        for (int bt = 0; bt < 4; ++bt) {
          float* p0 = &lds[(((z * 4 + 0) * 4 + bt) * 64 + lane) * 4];
          float* p1 = &lds[(((z * 4 + 1) * 4 + bt) * 64 + lane) * 4];
          float* p3 = &lds[(((z * 4 + 3) * 4 + bt) * 64 + lane) * 4];
          f32x4 v0 = *(f32x4*)p0; v0 += acc0[bt]; *(f32x4*)p0 = v0;
          f32x4 v1 = *(f32x4*)p1; v1 += acc1[bt]; *(f32x4*)p1 = v1;
          f32x4 v3 = *(f32x4*)p3; v3 += accn[bt]; *(f32x4*)p3 = v3;
        }
      }
      __syncthreads();
      // epilogue (R7-validated decode-0 + gate math)
      {
        const int wrt = (layer == 0) ? (s & 1) * (BATCH * HID) : ((s + 1) & 1) * (BATCH * HID);
        const int rdh = (layer == 0) ? ((s + 1) & 1) * (BATCH * HID) : (s & 1) * (BATCH * HID);
#pragma unroll
        for (int pp = 0; pp < 2; ++pp) {
          const int p = tid + pp * RNN_THREADS;  // (u,b): u = p>>6, b = p&63
          const int u = p >> 6, b = p & 63;
          const int l = ((u >> 2) << 4) | (b & 15);
          const int r = u & 3;
          const int bt = b >> 4;
          float sr = 0.f, sz = 0.f, sni = 0.f, snh = 0.f;
#pragma unroll
          for (int z = 0; z < 4; ++z) {
            sr  += lds[(((z * 4 + 0) * 4 + bt) * 64 + l) * 4 + r];
            sz  += lds[(((z * 4 + 1) * 4 + bt) * 64 + l) * 4 + r];
            sni += lds[(((z * 4 + 2) * 4 + bt) * 64 + l) * 4 + r];
            snh += lds[(((z * 4 + 3) * 4 + bt) * 64 + l) * 4 + r];
          }
          const int ug = ubase + u;
          const float rg = sigm(sr + bR[pp]);
          const float zg = sigm(sz + bZ[pp]);
          const float ng = tanhf(sni + bNi[pp] + rg * (snh + bNh[pp]));
          const float hp = hf[rdh + b * HID + ug];
          const float hn = (1.0f - zg) * ng + zg * hp;
          hf[wrt + b * HID + ug] = hn;
          const u16 hv = f2b(hn);
          hb[wrt + b * HID + ug] = hv;
          if (layer) h1all[((size_t)(s - 1) * BATCH + b) * HID + ug] = hv;
        }
      }
    }
    if (s < T_LEN) {  // R1-validated device-scope barrier between supersteps
      __syncthreads();
      if (tid == 0) {
        __threadfence();
        __hip_atomic_fetch_add(bar, 1u, __ATOMIC_ACQ_REL, __HIP_MEMORY_SCOPE_AGENT);
        const unsigned target = (unsigned)(s + 1) * NWG;
        while (__hip_atomic_load(bar, __ATOMIC_ACQUIRE, __HIP_MEMORY_SCOPE_AGENT) < target) { }
        __threadfence();
      }
      __syncthreads();
    }
  }
}

// -------- epilogue logits (R5-verified MFMA path, decode-0) --------
__global__ __launch_bounds__(256, 2) void logits_kernel(
    const u16* __restrict__ h1all, const u16* __restrict__ Woutb,
    const float* __restrict__ bout, float* __restrict__ out)
{
  __shared__ __align__(16) short lds[16 * 4 * 64 * 8];
  const int tid = (int)threadIdx.x;
  const int wv = tid >> 6, lane = tid & 63;
  const int lrow = lane & 15, lk8 = (lane >> 4) << 3;
  const int row0 = (int)blockIdx.x * 64 + wv * 16;
  f32x4 acc[16];
#pragma unroll
  for (int i = 0; i < 16; ++i) acc[i] = (f32x4){0.f, 0.f, 0.f, 0.f};

  for (int kc = 0; kc < HID; kc += 128) {
    __syncthreads();
#pragma unroll
    for (int j = 0; j < 16; ++j) {
      const int slot = tid + j * 256;
      const int ct = slot >> 8, kt = (slot >> 6) & 3, l = slot & 63;
      *(short8*)&lds[slot * 8] =
          *(const short8*)(Woutb + (size_t)(ct * 16 + (l & 15)) * HID + kc + kt * 32 + ((l >> 4) << 3));
    }
    __syncthreads();
#pragma unroll
    for (int kt = 0; kt < 4; ++kt) {
      const short8 af = *(const short8*)(h1all + (size_t)(row0 + lrow) * HID + kc + kt * 32 + lk8);
#pragma unroll
      for (int ct = 0; ct < 16; ++ct) {
        const short8 bf = *(const short8*)&lds[((ct * 4 + kt) * 64 + lane) * 8];
        acc[ct] = MFMA16(af, bf, acc[ct]);
      }
    }
  }
#pragma unroll
  for (int ct = 0; ct < 16; ++ct) {
    const int v = ct * 16 + lrow;
    const float bo = bout[v];
#pragma unroll
    for (int r = 0; r < 4; ++r) {
      const int row = row0 + (lane >> 4) * 4 + r;  // row = t*64 + b
      const int t = row >> 6, b = row & 63;
      out[((size_t)(b * T_LEN + t)) * VOC + v] = acc[ct][r] + bo;
    }
  }
}

extern "C" void kernel_launch(void* const* d_in, const int* in_sizes, int n_in,
                              void* d_out, int out_size, void* d_ws, size_t ws_size,
                              hipStream_t stream) {
  const int*   x     = (const int*)d_in[0];
  const float* embed = (const float*)d_in[1];
  const float* Wih0  = (const float*)d_in[2];
  const float* Whh0  = (const float*)d_in[3];
  const float* bih0  = (const float*)d_in[4];
  const float* bhh0  = (const float*)d_in[5];
  const float* Wih1  = (const float*)d_in[6];
  const float* Whh1  = (const float*)d_in[7];
  const float* bih1  = (const float*)d_in[8];
  const float* bhh1  = (const float*)d_in[9];
  const float* Wout  = (const float*)d_in[10];
  const float* bout  = (const float*)d_in[11];
  float* out = (float*)d_out;
  char* ws = (char*)d_ws;
  if (ws_size < (size_t)WS_TOTAL) return;

  hipMemsetAsync(ws, 0, ZERO_BYTES, stream);  // h-state double buffers + barrier
  cvt_kernel<<<1536, 256, 0, stream>>>(Wih0, (u16*)(ws + OFF_WIH0), 3072 * 512);
  cvt_kernel<<<3072, 256, 0, stream>>>(Whh0, (u16*)(ws + OFF_WHH0), 3072 * 1024);
  cvt_kernel<<<3072, 256, 0, stream>>>(Wih1, (u16*)(ws + OFF_WIH1), 3072 * 1024);
  cvt_kernel<<<3072, 256, 0, stream>>>(Whh1, (u16*)(ws + OFF_WHH1), 3072 * 1024);
  cvt_kernel<<<256, 256, 0, stream>>>(Wout, (u16*)(ws + OFF_WOUT), 256 * 1024);
  emb_kernel<<<8192, 256, 0, stream>>>(x, embed, (u16*)(ws + OFF_EMB));

  // host-side per-gate weight slices (rows: [0,H)=r, [H,2H)=z, [2H,3H)=n)
  const u16* wih0b = (const u16*)(ws + OFF_WIH0);
  const u16* whh0b = (const u16*)(ws + OFF_WHH0);
  const u16* wih1b = (const u16*)(ws + OFF_WIH1);
  const u16* whh1b = (const u16*)(ws + OFF_WHH1);

  rnn_persist_kernel<<<NWG, RNN_THREADS, 0, stream>>>(
      (const u16*)(ws + OFF_EMB),
      wih0b, wih0b + 524288, wih0b + 1048576,
      whh0b, whh0b + 1048576, whh0b + 2097152,
      wih1b, wih1b + 1048576, wih1b + 2097152,
      whh1b, whh1b + 1048576, whh1b + 2097152,
      bih0, bhh0, bih1, bhh1,
      (float*)(ws + OFF_H0F), (float*)(ws + OFF_H1F),
      (u16*)(ws + OFF_H0B), (u16*)(ws + OFF_H1B),
      (u16*)(ws + OFF_H1ALL), (unsigned*)(ws + OFF_BAR));

  logits_kernel<<<512, 256, 0, stream>>>((const u16*)(ws + OFF_H1ALL),
                                         (const u16*)(ws + OFF_WOUT), bout, out);
}

// Round 9
// 11224.808 us; speedup vs baseline: 1.5027x; 1.5027x over previous
//
#include <hip/hip_runtime.h>
#include <stdint.h>

typedef short short8 __attribute__((ext_vector_type(8)));
typedef float f32x4 __attribute__((ext_vector_type(4)));
typedef unsigned short u16;

#define MFMA16(a, b, c) __builtin_amdgcn_mfma_f32_16x16x32_bf16((a), (b), (c), 0, 0, 0)

#define T_LEN 512
#define BATCH 64
#define EMB_D 512
#define HID 1024
#define VOC 256
#define NWG 128
#define RNN_THREADS 512

// -------- workspace layout (bytes) --------
#define OFF_H0F   0u                         // float h0[2][64][1024]
#define OFF_H1F   524288u
#define OFF_H0B   1048576u                   // bf16 h0[2][64][1024]
#define OFF_H1B   1310720u
#define ZERO_BYTES 1573120u
#define OFF_EMB   1573120u                   // bf16 emb_all[512][64][512]
#define OFF_WIH0  (OFF_EMB + 33554432u)
#define OFF_WHH0  (OFF_WIH0 + 3145728u)
#define OFF_WIH1  (OFF_WHH0 + 6291456u)
#define OFF_WHH1  (OFF_WIH1 + 6291456u)
#define OFF_WOUT  (OFF_WHH1 + 6291456u)
#define OFF_H1ALL (OFF_WOUT + 524288u)       // bf16 h1_all[512*64][1024]
#define OFF_SYNC  (OFF_H1ALL + 67108864u)    // 128 flags (128B apart) + go word
#define SYNC_BYTES 16640u
#define WS_TOTAL  (OFF_SYNC + SYNC_BYTES)

static __device__ __forceinline__ u16 f2b(float f) {
  uint32_t u = __float_as_uint(f);
  u += 0x7FFFu + ((u >> 16) & 1u);   // round-to-nearest-even
  return (u16)(u >> 16);
}
static __device__ __forceinline__ float sigm(float x) { return 1.0f / (1.0f + __expf(-x)); }

// -------- f32 -> bf16 convert --------
__global__ void cvt_kernel(const float* __restrict__ src, u16* __restrict__ dst, int n) {
  int i = ((int)blockIdx.x * 256 + (int)threadIdx.x) * 4;
  if (i + 4 <= n) {
    const float4 v = *(const float4*)(src + i);
    ushort4 o;
    o.x = f2b(v.x); o.y = f2b(v.y); o.z = f2b(v.z); o.w = f2b(v.w);
    *(ushort4*)(dst + i) = o;
  }
}

// -------- embedding gather --------
__global__ void emb_kernel(const int* __restrict__ x, const float* __restrict__ embed,
                           u16* __restrict__ emb_all) {
  const int r = (int)blockIdx.x * 4 + ((int)threadIdx.x >> 6);
  const int c = ((int)threadIdx.x & 63) * 8;
  const int t = r >> 6, b = r & 63;
  const int xi = x[b * T_LEN + t];
  const float* s = embed + (size_t)xi * EMB_D + c;
  const float4 v0 = *(const float4*)s;
  const float4 v1 = *(const float4*)(s + 4);
  ushort4 lo, hi;
  lo.x = f2b(v0.x); lo.y = f2b(v0.y); lo.z = f2b(v0.z); lo.w = f2b(v0.w);
  hi.x = f2b(v1.x); hi.y = f2b(v1.y); hi.z = f2b(v1.z); hi.w = f2b(v1.w);
  u16* d = emb_all + (size_t)r * EMB_D + c;
  *(ushort4*)d = lo;
  *(ushort4*)(d + 4) = hi;
}

// -------- persistent RNN: superstep s = layer0(t=s) || layer1(t=s-1) --------
// 128 WGs, __launch_bounds__(512,1) so the 96 weight VGPRs stay resident.
// LDS layout: float idx = slot*256 + r*64 + (i ^ (r<<3)), slot=(zone*4+g)*4+bt.
// Barrier: per-WG flag lines + WG0 gather + go broadcast (no contended RMW).
__global__ __launch_bounds__(RNN_THREADS, 1) void rnn_persist_kernel(
    const u16* __restrict__ emb_all,
    const u16* __restrict__ A0i_r, const u16* __restrict__ A0i_z, const u16* __restrict__ A0i_n,
    const u16* __restrict__ A0h_r, const u16* __restrict__ A0h_z, const u16* __restrict__ A0h_n,
    const u16* __restrict__ A1i_r, const u16* __restrict__ A1i_z, const u16* __restrict__ A1i_n,
    const u16* __restrict__ A1h_r, const u16* __restrict__ A1h_z, const u16* __restrict__ A1h_n,
    const float* __restrict__ bih0, const float* __restrict__ bhh0,
    const float* __restrict__ bih1, const float* __restrict__ bhh1,
    float* __restrict__ h0f, float* __restrict__ h1f,
    u16* __restrict__ h0b, u16* __restrict__ h1b,
    u16* __restrict__ h1all, unsigned* __restrict__ sync)
{
  __shared__ __align__(16) float lds[16384];
  const int tid = (int)threadIdx.x;
  const int wv = tid >> 6;
  const int lane = tid & 63;
  const int lrow = lane & 15;
  const int lk8 = (lane >> 4) << 3;
  const int wgid = (int)blockIdx.x;
  const int layer = wgid >> 6;
  const int ubase = (wgid & 63) << 4;
  const bool iwave = (wv < 4);
  const bool l0i = (layer == 0) && iwave;
  unsigned* flags = sync;            // flags[wg] at sync[wg*32]
  unsigned* go = sync + NWG * 32;    // own line

  // ---- role-uniform A config ----
  const u16 *Ar, *Az, *An;
  int ldb, k0;
  if (layer == 0) {
    if (iwave) { Ar = A0i_r; Az = A0i_z; An = A0i_n; ldb = EMB_D; k0 = wv * 128; }
    else       { Ar = A0h_r; Az = A0h_z; An = A0h_n; ldb = HID;   k0 = (wv - 4) * 256; }
  } else {
    if (iwave) { Ar = A1i_r; Az = A1i_z; An = A1i_n; ldb = HID;   k0 = wv * 256; }
    else       { Ar = A1h_r; Az = A1h_z; An = A1h_n; ldb = HID;   k0 = (wv - 4) * 256; }
  }
  const size_t arow = (size_t)(ubase + lrow) * ldb;

  // ---- preload A fragments to registers (constant across time) ----
  short8 aR[8], aZ[8], aN[8];
  const int npre = l0i ? 4 : 8;
  for (int ks = 0; ks < npre; ++ks) {
    const int kk = k0 + ks * 32 + lk8;
    aR[ks] = *(const short8*)(Ar + arow + kk);
    aZ[ks] = *(const short8*)(Az + arow + kk);
    aN[ks] = *(const short8*)(An + arow + kk);
  }

  // ---- per-thread epilogue constants (u = tid&15 fixed across pp) ----
  const float* bi = layer ? bih1 : bih0;
  const float* bh = layer ? bhh1 : bhh0;
  const int eu = tid & 15;
  const int eug = ubase + eu;
  const float bR = bi[eug] + bh[eug];
  const float bZ = bi[HID + eug] + bh[HID + eug];
  const float bNi = bi[2 * HID + eug];
  const float bNh = bh[2 * HID + eug];
  const int el = ((eu >> 2) << 4);   // l high part; low nibble from b
  const int er = eu & 3;
  float* hf = layer ? h1f : h0f;
  u16* hb = layer ? h1b : h0b;

  for (int s = 0; s <= T_LEN; ++s) {
    const bool active = (layer == 0) ? (s < T_LEN) : (s >= 1);
    if (active) {
      const int rdA = ((s + 1) & 1) * (BATCH * HID);  // h0(s-1) slot
      const u16* Bp;
      if (layer == 0) Bp = iwave ? (emb_all + (size_t)s * (BATCH * EMB_D)) : (h0b + rdA);
      else            Bp = iwave ? (h0b + rdA) : (h1b + (s & 1) * (BATCH * HID));

      f32x4 acc0[4], acc1[4], accn[4];
#pragma unroll
      for (int bt = 0; bt < 4; ++bt) {
        acc0[bt] = (f32x4){0.f, 0.f, 0.f, 0.f};
        acc1[bt] = (f32x4){0.f, 0.f, 0.f, 0.f};
        accn[bt] = (f32x4){0.f, 0.f, 0.f, 0.f};
      }
      if (l0i) {
#pragma unroll
        for (int ks = 0; ks < 4; ++ks) {
          const int kk = k0 + ks * 32 + lk8;
#pragma unroll
          for (int bt = 0; bt < 4; ++bt) {
            const short8 bf = *(const short8*)(Bp + (size_t)(bt * 16 + lrow) * EMB_D + kk);
            acc0[bt] = MFMA16(aR[ks], bf, acc0[bt]);
            acc1[bt] = MFMA16(aZ[ks], bf, acc1[bt]);
            accn[bt] = MFMA16(aN[ks], bf, accn[bt]);
          }
        }
      } else {
#pragma unroll
        for (int ks = 0; ks < 8; ++ks) {
          const int kk = k0 + ks * 32 + lk8;
#pragma unroll
          for (int bt = 0; bt < 4; ++bt) {
            const short8 bf = *(const short8*)(Bp + (size_t)(bt * 16 + lrow) * HID + kk);
            acc0[bt] = MFMA16(aR[ks], bf, acc0[bt]);
            acc1[bt] = MFMA16(aZ[ks], bf, acc1[bt]);
            accn[bt] = MFMA16(aN[ks], bf, accn[bt]);
          }
        }
      }
      // reduction round 1: i-waves store groups {0,1,2}; conflict-free scalar stores
      if (iwave) {
#pragma unroll
        for (int bt = 0; bt < 4; ++bt)
#pragma unroll
          for (int r = 0; r < 4; ++r) {
            const int ix = lane ^ (r << 3);
            lds[(((wv * 4 + 0) * 4 + bt) * 256) + r * 64 + ix] = acc0[bt][r];
            lds[(((wv * 4 + 1) * 4 + bt) * 256) + r * 64 + ix] = acc1[bt][r];
            lds[(((wv * 4 + 2) * 4 + bt) * 256) + r * 64 + ix] = accn[bt][r];
          }
      }
      __syncthreads();
      // reduction round 2: h-waves add groups {0,1}, store group 3
      if (!iwave) {
        const int z = wv - 4;
#pragma unroll
        for (int bt = 0; bt < 4; ++bt)
#pragma unroll
          for (int r = 0; r < 4; ++r) {
            const int ix = lane ^ (r << 3);
            float* p0 = &lds[(((z * 4 + 0) * 4 + bt) * 256) + r * 64 + ix];
            float* p1 = &lds[(((z * 4 + 1) * 4 + bt) * 256) + r * 64 + ix];
            *p0 = *p0 + acc0[bt][r];
            *p1 = *p1 + acc1[bt][r];
            lds[(((z * 4 + 3) * 4 + bt) * 256) + r * 64 + ix] = accn[bt][r];
          }
      }
      __syncthreads();
      // epilogue: coalesced mapping u = p&15, b = (p>>4)&63
      {
        const int wrt = (layer == 0) ? (s & 1) * (BATCH * HID) : ((s + 1) & 1) * (BATCH * HID);
        const int rdh = (layer == 0) ? ((s + 1) & 1) * (BATCH * HID) : (s & 1) * (BATCH * HID);
#pragma unroll
        for (int pp = 0; pp < 2; ++pp) {
          const int p = tid + pp * RNN_THREADS;
          const int b = (p >> 4) & 63;
          const int l = el | (b & 15);
          const int bt = b >> 4;
          const int ix = l ^ (er << 3);
          float sr = 0.f, sz = 0.f, sni = 0.f, snh = 0.f;
#pragma unroll
          for (int z = 0; z < 4; ++z) {
            sr  += lds[(((z * 4 + 0) * 4 + bt) * 256) + er * 64 + ix];
            sz  += lds[(((z * 4 + 1) * 4 + bt) * 256) + er * 64 + ix];
            sni += lds[(((z * 4 + 2) * 4 + bt) * 256) + er * 64 + ix];
            snh += lds[(((z * 4 + 3) * 4 + bt) * 256) + er * 64 + ix];
          }
          const float rg = sigm(sr + bR);
          const float zg = sigm(sz + bZ);
          const float ng = tanhf(sni + bNi + rg * (snh + bNh));
          const float hp = hf[rdh + b * HID + eug];
          const float hn = (1.0f - zg) * ng + zg * hp;
          hf[wrt + b * HID + eug] = hn;
          const u16 hv = f2b(hn);
          hb[wrt + b * HID + eug] = hv;
          if (layer) h1all[((size_t)(s - 1) * BATCH + b) * HID + eug] = hv;
        }
      }
    }
    if (s < T_LEN) {  // flag-array barrier (release/acquire message passing)
      __syncthreads();
      const unsigned ep = (unsigned)(s + 1);
      if (wgid == 0) {
        if (tid == 0)
          __hip_atomic_store(&flags[0], ep, __ATOMIC_RELEASE, __HIP_MEMORY_SCOPE_AGENT);
        if (tid < NWG) {
          while (__hip_atomic_load(&flags[tid * 32], __ATOMIC_ACQUIRE,
                                   __HIP_MEMORY_SCOPE_AGENT) < ep)
            __builtin_amdgcn_s_sleep(2);
        }
        __syncthreads();
        if (tid == 0)
          __hip_atomic_store(go, ep, __ATOMIC_RELEASE, __HIP_MEMORY_SCOPE_AGENT);
      } else {
        if (tid == 0) {
          __hip_atomic_store(&flags[wgid * 32], ep, __ATOMIC_RELEASE, __HIP_MEMORY_SCOPE_AGENT);
          while (__hip_atomic_load(go, __ATOMIC_ACQUIRE, __HIP_MEMORY_SCOPE_AGENT) < ep)
            __builtin_amdgcn_s_sleep(2);
        }
        __syncthreads();
      }
    }
  }
}

// -------- epilogue logits (R5-verified MFMA path, decode-0) --------
__global__ __launch_bounds__(256, 2) void logits_kernel(
    const u16* __restrict__ h1all, const u16* __restrict__ Woutb,
    const float* __restrict__ bout, float* __restrict__ out)
{
  __shared__ __align__(16) short lds[16 * 4 * 64 * 8];
  const int tid = (int)threadIdx.x;
  const int wv = tid >> 6, lane = tid & 63;
  const int lrow = lane & 15, lk8 = (lane >> 4) << 3;
  const int row0 = (int)blockIdx.x * 64 + wv * 16;
  f32x4 acc[16];
#pragma unroll
  for (int i = 0; i < 16; ++i) acc[i] = (f32x4){0.f, 0.f, 0.f, 0.f};

  for (int kc = 0; kc < HID; kc += 128) {
    __syncthreads();
#pragma unroll
    for (int j = 0; j < 16; ++j) {
      const int slot = tid + j * 256;
      const int ct = slot >> 8, kt = (slot >> 6) & 3, l = slot & 63;
      *(short8*)&lds[slot * 8] =
          *(const short8*)(Woutb + (size_t)(ct * 16 + (l & 15)) * HID + kc + kt * 32 + ((l >> 4) << 3));
    }
    __syncthreads();
#pragma unroll
    for (int kt = 0; kt < 4; ++kt) {
      const short8 af = *(const short8*)(h1all + (size_t)(row0 + lrow) * HID + kc + kt * 32 + lk8);
#pragma unroll
      for (int ct = 0; ct < 16; ++ct) {
        const short8 bf = *(const short8*)&lds[((ct * 4 + kt) * 64 + lane) * 8];
        acc[ct] = MFMA16(af, bf, acc[ct]);
      }
    }
  }
#pragma unroll
  for (int ct = 0; ct < 16; ++ct) {
    const int v = ct * 16 + lrow;
    const float bo = bout[v];
#pragma unroll
    for (int r = 0; r < 4; ++r) {
      const int row = row0 + (lane >> 4) * 4 + r;  // row = t*64 + b
      const int t = row >> 6, b = row & 63;
      out[((size_t)(b * T_LEN + t)) * VOC + v] = acc[ct][r] + bo;
    }
  }
}

extern "C" void kernel_launch(void* const* d_in, const int* in_sizes, int n_in,
                              void* d_out, int out_size, void* d_ws, size_t ws_size,
                              hipStream_t stream) {
  const int*   x     = (const int*)d_in[0];
  const float* embed = (const float*)d_in[1];
  const float* Wih0  = (const float*)d_in[2];
  const float* Whh0  = (const float*)d_in[3];
  const float* bih0  = (const float*)d_in[4];
  const float* bhh0  = (const float*)d_in[5];
  const float* Wih1  = (const float*)d_in[6];
  const float* Whh1  = (const float*)d_in[7];
  const float* bih1  = (const float*)d_in[8];
  const float* bhh1  = (const float*)d_in[9];
  const float* Wout  = (const float*)d_in[10];
  const float* bout  = (const float*)d_in[11];
  float* out = (float*)d_out;
  char* ws = (char*)d_ws;
  if (ws_size < (size_t)WS_TOTAL) return;

  hipMemsetAsync(ws, 0, ZERO_BYTES, stream);            // h-state double buffers
  hipMemsetAsync(ws + OFF_SYNC, 0, SYNC_BYTES, stream); // barrier flags + go
  cvt_kernel<<<1536, 256, 0, stream>>>(Wih0, (u16*)(ws + OFF_WIH0), 3072 * 512);
  cvt_kernel<<<3072, 256, 0, stream>>>(Whh0, (u16*)(ws + OFF_WHH0), 3072 * 1024);
  cvt_kernel<<<3072, 256, 0, stream>>>(Wih1, (u16*)(ws + OFF_WIH1), 3072 * 1024);
  cvt_kernel<<<3072, 256, 0, stream>>>(Whh1, (u16*)(ws + OFF_WHH1), 3072 * 1024);
  cvt_kernel<<<256, 256, 0, stream>>>(Wout, (u16*)(ws + OFF_WOUT), 256 * 1024);
  emb_kernel<<<8192, 256, 0, stream>>>(x, embed, (u16*)(ws + OFF_EMB));

  const u16* wih0b = (const u16*)(ws + OFF_WIH0);
  const u16* whh0b = (const u16*)(ws + OFF_WHH0);
  const u16* wih1b = (const u16*)(ws + OFF_WIH1);
  const u16* whh1b = (const u16*)(ws + OFF_WHH1);

  rnn_persist_kernel<<<NWG, RNN_THREADS, 0, stream>>>(
      (const u16*)(ws + OFF_EMB),
      wih0b, wih0b + 524288, wih0b + 1048576,
      whh0b, whh0b + 1048576, whh0b + 2097152,
      wih1b, wih1b + 1048576, wih1b + 2097152,
      whh1b, whh1b + 1048576, whh1b + 2097152,
      bih0, bhh0, bih1, bhh1,
      (float*)(ws + OFF_H0F), (float*)(ws + OFF_H1F),
      (u16*)(ws + OFF_H0B), (u16*)(ws + OFF_H1B),
      (u16*)(ws + OFF_H1ALL), (unsigned*)(ws + OFF_SYNC));

  logits_kernel<<<512, 256, 0, stream>>>((const u16*)(ws + OFF_H1ALL),
                                         (const u16*)(ws + OFF_WOUT), bout, out);
}

// Round 10
// 8112.444 us; speedup vs baseline: 2.0793x; 1.3837x over previous
//
#include <hip/hip_runtime.h>
#include <stdint.h>

typedef short short8 __attribute__((ext_vector_type(8)));
typedef float f32x4 __attribute__((ext_vector_type(4)));
typedef unsigned short u16;

#define MFMA16(a, b, c) __builtin_amdgcn_mfma_f32_16x16x32_bf16((a), (b), (c), 0, 0, 0)

#define T_LEN 512
#define BATCH 64
#define EMB_D 512
#define HID 1024
#define VOC 256
#define NWG 128
#define RNN_THREADS 512

// -------- workspace layout (bytes) --------
#define OFF_H0B   1048576u                   // bf16 h0[2][64][1024]
#define OFF_H1B   1310720u                   // bf16 h1[2][64][1024]
#define HB_ZERO_BYTES 524288u                // h0b+h1b contiguous
#define OFF_EMB   1573120u                   // bf16 emb_all[512][64][512]
#define OFF_WIH0  (OFF_EMB + 33554432u)
#define OFF_WHH0  (OFF_WIH0 + 3145728u)
#define OFF_WIH1  (OFF_WHH0 + 6291456u)
#define OFF_WHH1  (OFF_WIH1 + 6291456u)
#define OFF_WOUT  (OFF_WHH1 + 6291456u)
#define OFF_H1ALL (OFF_WOUT + 524288u)       // bf16 h1_all[512*64][1024]
#define OFF_SYNC  (OFF_H1ALL + 67108864u)    // 128 flag lines (128B apart)
#define SYNC_BYTES 16640u
#define WS_TOTAL  (OFF_SYNC + SYNC_BYTES)

static __device__ __forceinline__ u16 f2b(float f) {
  uint32_t u = __float_as_uint(f);
  u += 0x7FFFu + ((u >> 16) & 1u);   // round-to-nearest-even
  return (u16)(u >> 16);
}
static __device__ __forceinline__ float sigm(float x) { return 1.0f / (1.0f + __expf(-x)); }

// -------- f32 -> bf16 convert --------
__global__ void cvt_kernel(const float* __restrict__ src, u16* __restrict__ dst, int n) {
  int i = ((int)blockIdx.x * 256 + (int)threadIdx.x) * 4;
  if (i + 4 <= n) {
    const float4 v = *(const float4*)(src + i);
    ushort4 o;
    o.x = f2b(v.x); o.y = f2b(v.y); o.z = f2b(v.z); o.w = f2b(v.w);
    *(ushort4*)(dst + i) = o;
  }
}

// -------- embedding gather --------
__global__ void emb_kernel(const int* __restrict__ x, const float* __restrict__ embed,
                           u16* __restrict__ emb_all) {
  const int r = (int)blockIdx.x * 4 + ((int)threadIdx.x >> 6);
  const int c = ((int)threadIdx.x & 63) * 8;
  const int t = r >> 6, b = r & 63;
  const int xi = x[b * T_LEN + t];
  const float* s = embed + (size_t)xi * EMB_D + c;
  const float4 v0 = *(const float4*)s;
  const float4 v1 = *(const float4*)(s + 4);
  ushort4 lo, hi;
  lo.x = f2b(v0.x); lo.y = f2b(v0.y); lo.z = f2b(v0.z); lo.w = f2b(v0.w);
  hi.x = f2b(v1.x); hi.y = f2b(v1.y); hi.z = f2b(v1.z); hi.w = f2b(v1.w);
  u16* d = emb_all + (size_t)r * EMB_D + c;
  *(ushort4*)d = lo;
  *(ushort4*)(d + 4) = hi;
}

// -------- persistent RNN: superstep s = layer0(t=s) || layer1(t=s-1) --------
// 128 WGs, __launch_bounds__(512,1): VGPR budget 256 so weight fragments are
// register-resident (STATIC preload, compile-time indices only).
// Master h state for this thread's (unit,batch) pairs lives in hprev[2] regs.
// Barrier: all-to-all flag lines, one L3 hop (no WG0 gather, no RMW).
__global__ __launch_bounds__(RNN_THREADS, 1) void rnn_persist_kernel(
    const u16* __restrict__ emb_all,
    const u16* __restrict__ A0i_r, const u16* __restrict__ A0i_z, const u16* __restrict__ A0i_n,
    const u16* __restrict__ A0h_r, const u16* __restrict__ A0h_z, const u16* __restrict__ A0h_n,
    const u16* __restrict__ A1i_r, const u16* __restrict__ A1i_z, const u16* __restrict__ A1i_n,
    const u16* __restrict__ A1h_r, const u16* __restrict__ A1h_z, const u16* __restrict__ A1h_n,
    const float* __restrict__ bih0, const float* __restrict__ bhh0,
    const float* __restrict__ bih1, const float* __restrict__ bhh1,
    u16* __restrict__ h0b, u16* __restrict__ h1b,
    u16* __restrict__ h1all, unsigned* __restrict__ flags)
{
  __shared__ __align__(16) float lds[16384];
  const int tid = (int)threadIdx.x;
  const int wv = tid >> 6;
  const int lane = tid & 63;
  const int lrow = lane & 15;
  const int lk8 = (lane >> 4) << 3;
  const int wgid = (int)blockIdx.x;
  const int layer = wgid >> 6;
  const int ubase = (wgid & 63) << 4;
  const bool iwave = (wv < 4);
  const bool l0i = (layer == 0) && iwave;

  // ---- role-uniform A config ----
  const u16 *Ar, *Az, *An;
  int ldb, k0;
  if (layer == 0) {
    if (iwave) { Ar = A0i_r; Az = A0i_z; An = A0i_n; ldb = EMB_D; k0 = wv * 128; }
    else       { Ar = A0h_r; Az = A0h_z; An = A0h_n; ldb = HID;   k0 = (wv - 4) * 256; }
  } else {
    if (iwave) { Ar = A1i_r; Az = A1i_z; An = A1i_n; ldb = HID;   k0 = wv * 256; }
    else       { Ar = A1h_r; Az = A1h_z; An = A1h_n; ldb = HID;   k0 = (wv - 4) * 256; }
  }
  const size_t arow = (size_t)(ubase + lrow) * ldb;

  // ---- STATIC preload of A fragments (all indices compile-time) ----
  short8 a4R[4], a4Z[4], a4N[4];   // l0i path (K=512 slice)
  short8 a8R[8], a8Z[8], a8N[8];   // all other paths (K=1024 slice)
  if (l0i) {
#pragma unroll
    for (int ks = 0; ks < 4; ++ks) {
      const int kk = k0 + ks * 32 + lk8;
      a4R[ks] = *(const short8*)(Ar + arow + kk);
      a4Z[ks] = *(const short8*)(Az + arow + kk);
      a4N[ks] = *(const short8*)(An + arow + kk);
    }
  } else {
#pragma unroll
    for (int ks = 0; ks < 8; ++ks) {
      const int kk = k0 + ks * 32 + lk8;
      a8R[ks] = *(const short8*)(Ar + arow + kk);
      a8Z[ks] = *(const short8*)(Az + arow + kk);
      a8N[ks] = *(const short8*)(An + arow + kk);
    }
  }

  // ---- per-thread epilogue constants; master h in registers ----
  const float* bi = layer ? bih1 : bih0;
  const float* bh = layer ? bhh1 : bhh0;
  const int eu = tid & 15;
  const int eug = ubase + eu;
  const float bR = bi[eug] + bh[eug];
  const float bZ = bi[HID + eug] + bh[HID + eug];
  const float bNi = bi[2 * HID + eug];
  const float bNh = bh[2 * HID + eug];
  const int el = ((eu >> 2) << 4);
  const int er = eu & 3;
  u16* hb = layer ? h1b : h0b;
  float hprev[2] = {0.f, 0.f};     // static-indexed via unrolled pp loop

  for (int s = 0; s <= T_LEN; ++s) {
    const bool active = (layer == 0) ? (s < T_LEN) : (s >= 1);
    if (active) {
      const int rdA = ((s + 1) & 1) * (BATCH * HID);  // h0(s-1) slot
      const u16* Bp;
      if (layer == 0) Bp = iwave ? (emb_all + (size_t)s * (BATCH * EMB_D)) : (h0b + rdA);
      else            Bp = iwave ? (h0b + rdA) : (h1b + (s & 1) * (BATCH * HID));

      f32x4 acc0[4], acc1[4], accn[4];
#pragma unroll
      for (int bt = 0; bt < 4; ++bt) {
        acc0[bt] = (f32x4){0.f, 0.f, 0.f, 0.f};
        acc1[bt] = (f32x4){0.f, 0.f, 0.f, 0.f};
        accn[bt] = (f32x4){0.f, 0.f, 0.f, 0.f};
      }
      if (l0i) {
#pragma unroll
        for (int ks = 0; ks < 4; ++ks) {
          const int kk = k0 + ks * 32 + lk8;
#pragma unroll
          for (int bt = 0; bt < 4; ++bt) {
            const short8 bf = *(const short8*)(Bp + (size_t)(bt * 16 + lrow) * EMB_D + kk);
            acc0[bt] = MFMA16(a4R[ks], bf, acc0[bt]);
            acc1[bt] = MFMA16(a4Z[ks], bf, acc1[bt]);
            accn[bt] = MFMA16(a4N[ks], bf, accn[bt]);
          }
        }
      } else {
#pragma unroll
        for (int ks = 0; ks < 8; ++ks) {
          const int kk = k0 + ks * 32 + lk8;
#pragma unroll
          for (int bt = 0; bt < 4; ++bt) {
            const short8 bf = *(const short8*)(Bp + (size_t)(bt * 16 + lrow) * HID + kk);
            acc0[bt] = MFMA16(a8R[ks], bf, acc0[bt]);
            acc1[bt] = MFMA16(a8Z[ks], bf, acc1[bt]);
            accn[bt] = MFMA16(a8N[ks], bf, accn[bt]);
          }
        }
      }
      // reduction round 1: i-waves store groups {0,1,2} (XOR-swizzled, conflict-free)
      if (iwave) {
#pragma unroll
        for (int bt = 0; bt < 4; ++bt)
#pragma unroll
          for (int r = 0; r < 4; ++r) {
            const int ix = lane ^ (r << 3);
            lds[(((wv * 4 + 0) * 4 + bt) * 256) + r * 64 + ix] = acc0[bt][r];
            lds[(((wv * 4 + 1) * 4 + bt) * 256) + r * 64 + ix] = acc1[bt][r];
            lds[(((wv * 4 + 2) * 4 + bt) * 256) + r * 64 + ix] = accn[bt][r];
          }
      }
      __syncthreads();
      // reduction round 2: h-waves add groups {0,1}, store group 3
      if (!iwave) {
        const int z = wv - 4;
#pragma unroll
        for (int bt = 0; bt < 4; ++bt)
#pragma unroll
          for (int r = 0; r < 4; ++r) {
            const int ix = lane ^ (r << 3);
            float* p0 = &lds[(((z * 4 + 0) * 4 + bt) * 256) + r * 64 + ix];
            float* p1 = &lds[(((z * 4 + 1) * 4 + bt) * 256) + r * 64 + ix];
            *p0 = *p0 + acc0[bt][r];
            *p1 = *p1 + acc1[bt][r];
            lds[(((z * 4 + 3) * 4 + bt) * 256) + r * 64 + ix] = accn[bt][r];
          }
      }
      __syncthreads();
      // epilogue: coalesced (u = p&15), master h in registers
      {
        const int wrt = (layer == 0) ? (s & 1) * (BATCH * HID) : ((s + 1) & 1) * (BATCH * HID);
#pragma unroll
        for (int pp = 0; pp < 2; ++pp) {
          const int p = tid + pp * RNN_THREADS;
          const int b = (p >> 4) & 63;
          const int l = el | (b & 15);
          const int bt = b >> 4;
          const int ix = l ^ (er << 3);
          float sr = 0.f, sz = 0.f, sni = 0.f, snh = 0.f;
#pragma unroll
          for (int z = 0; z < 4; ++z) {
            sr  += lds[(((z * 4 + 0) * 4 + bt) * 256) + er * 64 + ix];
            sz  += lds[(((z * 4 + 1) * 4 + bt) * 256) + er * 64 + ix];
            sni += lds[(((z * 4 + 2) * 4 + bt) * 256) + er * 64 + ix];
            snh += lds[(((z * 4 + 3) * 4 + bt) * 256) + er * 64 + ix];
          }
          const float rg = sigm(sr + bR);
          const float zg = sigm(sz + bZ);
          const float ng = tanhf(sni + bNi + rg * (snh + bNh));
          const float hn = (1.0f - zg) * ng + zg * hprev[pp];
          hprev[pp] = hn;
          const u16 hv = f2b(hn);
          hb[wrt + b * HID + eug] = hv;
          if (layer) h1all[((size_t)(s - 1) * BATCH + b) * HID + eug] = hv;
        }
      }
    }
    if (s < T_LEN) {  // all-to-all flag barrier: one release hop, parallel polls
      __syncthreads();
      const unsigned ep = (unsigned)(s + 1);
      if (tid == 0)
        __hip_atomic_store(&flags[wgid * 32], ep, __ATOMIC_RELEASE, __HIP_MEMORY_SCOPE_AGENT);
      if (tid < NWG) {
        while (__hip_atomic_load(&flags[tid * 32], __ATOMIC_ACQUIRE,
                                 __HIP_MEMORY_SCOPE_AGENT) < ep)
          __builtin_amdgcn_s_sleep(1);
      }
      __syncthreads();
    }
  }
}

// -------- epilogue logits (R5-verified MFMA path, decode-0) --------
__global__ __launch_bounds__(256, 2) void logits_kernel(
    const u16* __restrict__ h1all, const u16* __restrict__ Woutb,
    const float* __restrict__ bout, float* __restrict__ out)
{
  __shared__ __align__(16) short lds[16 * 4 * 64 * 8];
  const int tid = (int)threadIdx.x;
  const int wv = tid >> 6, lane = tid & 63;
  const int lrow = lane & 15, lk8 = (lane >> 4) << 3;
  const int row0 = (int)blockIdx.x * 64 + wv * 16;
  f32x4 acc[16];
#pragma unroll
  for (int i = 0; i < 16; ++i) acc[i] = (f32x4){0.f, 0.f, 0.f, 0.f};

  for (int kc = 0; kc < HID; kc += 128) {
    __syncthreads();
#pragma unroll
    for (int j = 0; j < 16; ++j) {
      const int slot = tid + j * 256;
      const int ct = slot >> 8, kt = (slot >> 6) & 3, l = slot & 63;
      *(short8*)&lds[slot * 8] =
          *(const short8*)(Woutb + (size_t)(ct * 16 + (l & 15)) * HID + kc + kt * 32 + ((l >> 4) << 3));
    }
    __syncthreads();
#pragma unroll
    for (int kt = 0; kt < 4; ++kt) {
      const short8 af = *(const short8*)(h1all + (size_t)(row0 + lrow) * HID + kc + kt * 32 + lk8);
#pragma unroll
      for (int ct = 0; ct < 16; ++ct) {
        const short8 bf = *(const short8*)&lds[((ct * 4 + kt) * 64 + lane) * 8];
        acc[ct] = MFMA16(af, bf, acc[ct]);
      }
    }
  }
#pragma unroll
  for (int ct = 0; ct < 16; ++ct) {
    const int v = ct * 16 + lrow;
    const float bo = bout[v];
#pragma unroll
    for (int r = 0; r < 4; ++r) {
      const int row = row0 + (lane >> 4) * 4 + r;  // row = t*64 + b
      const int t = row >> 6, b = row & 63;
      out[((size_t)(b * T_LEN + t)) * VOC + v] = acc[ct][r] + bo;
    }
  }
}

extern "C" void kernel_launch(void* const* d_in, const int* in_sizes, int n_in,
                              void* d_out, int out_size, void* d_ws, size_t ws_size,
                              hipStream_t stream) {
  const int*   x     = (const int*)d_in[0];
  const float* embed = (const float*)d_in[1];
  const float* Wih0  = (const float*)d_in[2];
  const float* Whh0  = (const float*)d_in[3];
  const float* bih0  = (const float*)d_in[4];
  const float* bhh0  = (const float*)d_in[5];
  const float* Wih1  = (const float*)d_in[6];
  const float* Whh1  = (const float*)d_in[7];
  const float* bih1  = (const float*)d_in[8];
  const float* bhh1  = (const float*)d_in[9];
  const float* Wout  = (const float*)d_in[10];
  const float* bout  = (const float*)d_in[11];
  float* out = (float*)d_out;
  char* ws = (char*)d_ws;
  if (ws_size < (size_t)WS_TOTAL) return;

  hipMemsetAsync(ws + OFF_H0B, 0, HB_ZERO_BYTES, stream);  // bf16 h double buffers
  hipMemsetAsync(ws + OFF_SYNC, 0, SYNC_BYTES, stream);    // barrier flags
  cvt_kernel<<<1536, 256, 0, stream>>>(Wih0, (u16*)(ws + OFF_WIH0), 3072 * 512);
  cvt_kernel<<<3072, 256, 0, stream>>>(Whh0, (u16*)(ws + OFF_WHH0), 3072 * 1024);
  cvt_kernel<<<3072, 256, 0, stream>>>(Wih1, (u16*)(ws + OFF_WIH1), 3072 * 1024);
  cvt_kernel<<<3072, 256, 0, stream>>>(Whh1, (u16*)(ws + OFF_WHH1), 3072 * 1024);
  cvt_kernel<<<256, 256, 0, stream>>>(Wout, (u16*)(ws + OFF_WOUT), 256 * 1024);
  emb_kernel<<<8192, 256, 0, stream>>>(x, embed, (u16*)(ws + OFF_EMB));

  const u16* wih0b = (const u16*)(ws + OFF_WIH0);
  const u16* whh0b = (const u16*)(ws + OFF_WHH0);
  const u16* wih1b = (const u16*)(ws + OFF_WIH1);
  const u16* whh1b = (const u16*)(ws + OFF_WHH1);

  rnn_persist_kernel<<<NWG, RNN_THREADS, 0, stream>>>(
      (const u16*)(ws + OFF_EMB),
      wih0b, wih0b + 524288, wih0b + 1048576,
      whh0b, whh0b + 1048576, whh0b + 2097152,
      wih1b, wih1b + 1048576, wih1b + 2097152,
      whh1b, whh1b + 1048576, whh1b + 2097152,
      bih0, bhh0, bih1, bhh1,
      (u16*)(ws + OFF_H0B), (u16*)(ws + OFF_H1B),
      (u16*)(ws + OFF_H1ALL), (unsigned*)(ws + OFF_SYNC));

  logits_kernel<<<512, 256, 0, stream>>>((const u16*)(ws + OFF_H1ALL),
                                         (const u16*)(ws + OFF_WOUT), bout, out);
}